// Round 4
// baseline (517.728 us; speedup 1.0000x reference)
//
#include <hip/hip_runtime.h>
#include <hip/hip_bf16.h>
#include <cstdint>
#include <cstddef>

#define EMBED 1024
#define SLEN  2048
#define NB    2
#define HEADS 16
#define HDIM  64
#define FFDIM 4096
#define ROWS  (NB * SLEN)   // 4096
#define LOG2E 1.4426950408889634f

typedef __attribute__((ext_vector_type(8))) __bf16 bf16x8;
typedef __attribute__((ext_vector_type(4))) __bf16 bf16x4;
typedef __attribute__((ext_vector_type(4))) float  f32x4;

__device__ __forceinline__ void gload_lds16(const void* g, void* l) {
  __builtin_amdgcn_global_load_lds(
      (const __attribute__((address_space(1))) void*)g,
      (__attribute__((address_space(3))) void*)l, 16, 0, 0);
}

// ---------------- cast x: f32 -> bf16 (row-major) ----------------
__global__ __launch_bounds__(256) void cast_f32_bf16(const float* __restrict__ in,
                                                     __bf16* __restrict__ out, int n4) {
  int i = blockIdx.x * 256 + threadIdx.x;
  if (i >= n4) return;
  float4 v = ((const float4*)in)[i];
  bf16x4 o;
  o.x = (__bf16)v.x; o.y = (__bf16)v.y; o.z = (__bf16)v.z; o.w = (__bf16)v.w;
  ((bf16x4*)out)[i] = o;
}

// ---------------- transpose + cast: in[R][C] f32 -> out[C][R] bf16 ----------------
__global__ __launch_bounds__(256) void transpose_cast(const float* __restrict__ in,
                                                      __bf16* __restrict__ out, int R, int C) {
  __shared__ float t[64][65];
  const int tx = threadIdx.x & 63;
  const int ty = threadIdx.x >> 6;  // 0..3
  const int tr = blockIdx.y * 64;   // row tile (R dim)
  const int tc = blockIdx.x * 64;   // col tile (C dim)
#pragma unroll
  for (int i = 0; i < 16; ++i) {
    int a = ty * 16 + i;
    t[a][tx] = in[(size_t)(tr + a) * C + tc + tx];
  }
  __syncthreads();
#pragma unroll
  for (int i = 0; i < 16; ++i) {
    int b = ty * 16 + i;
    out[(size_t)(tc + b) * R + tr + tx] = (__bf16)t[tx][b];
  }
}

// ---------------- mask tile flags: 1 iff all mask!=0 in 128q x 64k tile ----------
// flags[(n*16 + qt)*32 + kt]
__global__ __launch_bounds__(256) void mask_flags_k(const int* __restrict__ mask,
                                                    int* __restrict__ flags) {
  const int b = blockIdx.x;
  const int kt = b & 31, qt = (b >> 5) & 15, n = b >> 9;
  const int tid = threadIdx.x;
  const int* base = mask + ((size_t)n * SLEN + qt * 128) * SLEN + kt * 64;
  const int rw = tid >> 4;
  const int cg = tid & 15;
  int ok = 1;
#pragma unroll
  for (int i = 0; i < 8; ++i) {
    int4 v = ((const int4*)(base + (size_t)(rw + i * 16) * SLEN))[cg];
    ok &= (v.x != 0) & (v.y != 0) & (v.z != 0) & (v.w != 0);
  }
  __shared__ int red;
  if (tid == 0) red = 1;
  __syncthreads();
  if (!ok) red = 0;  // benign race: all writers store 0
  __syncthreads();
  if (tid == 0) flags[b] = red;
}

// ---------------- GEMM: C[M][N] = A[M][K] * Bt[N][K]^T ----------------------------
// MODE 3: out bf16 row-major = relu(acc + bias)
// MODE 4: fused QKV: N=3072; sel=col>>10: 0 -> Q layout [n][h][s][d] * oscale,
//         1 -> K layout [n][h][s][d], 2 -> Vt layout [n][h][d][s]; bias/bias2/bias3.
// MODE 5: split-K partial: grid = tiles*ksplit; kz = bid/tiles; computes K-chunk
//         [kz*Kc, (kz+1)*Kc) and writes raw f32 acc to outp[kz*M*N + row*N + col].
template <int MODE>
__global__ __launch_bounds__(256, 2) void gemm_bt(
    const __bf16* __restrict__ A, const __bf16* __restrict__ Bt,
    const float* __restrict__ bias, const float* __restrict__ bias2,
    const float* __restrict__ bias3,
    void* __restrict__ outp, void* __restrict__ outp2, void* __restrict__ outp3,
    int M, int N, int K, int Kc, float oscale) {
  __shared__ __bf16 lds[2][2][4][128][8];
  const int tid = threadIdx.x;
  const int lane = tid & 63;
  const int ntile = N >> 7;
  int t = blockIdx.x;
  int kz = 0;
  if constexpr (MODE == 5) {
    const int tiles = (M >> 7) * ntile;
    kz = t / tiles;
    t -= kz * tiles;
  }
  const int bm = t / ntile;
  const int bn = t % ntile;
  const int trow = bm << 7;
  const int tcol = bn << 7;

  const int c0 = tid >> 7;
  const int r0 = tid & 127;
  const __bf16* Ag = A + (size_t)(trow + r0) * K + (size_t)kz * Kc + c0 * 8;
  const __bf16* Bg = Bt + (size_t)(tcol + r0) * K + (size_t)kz * Kc + c0 * 8;

  auto stage = [&](int buf, int kt) {
    const __bf16* a0 = Ag + (size_t)kt * 32;
    const __bf16* b0 = Bg + (size_t)kt * 32;
    char* la = (char*)&lds[buf][0][0][0][0] + tid * 16;
    char* lb = (char*)&lds[buf][1][0][0][0] + tid * 16;
    gload_lds16(a0, la);
    gload_lds16(a0 + 16, la + 4096);
    gload_lds16(b0, lb);
    gload_lds16(b0 + 16, lb + 4096);
  };

  const int wave = tid >> 6;
  const int wr = (wave >> 1) * 64;
  const int wc = (wave & 1) * 64;
  const int l16 = lane & 15;
  const int g4 = lane >> 4;

  f32x4 acc[4][4];
#pragma unroll
  for (int i = 0; i < 4; ++i)
#pragma unroll
    for (int j = 0; j < 4; ++j) acc[i][j] = (f32x4)0.0f;

  const int nk = Kc >> 5;
  stage(0, 0);
  for (int kt = 0; kt < nk; ++kt) {
    const int cur = kt & 1;
    if (kt + 1 < nk) stage(cur ^ 1, kt + 1);
    __syncthreads();
    bf16x8 af[4], bfr[4];
#pragma unroll
    for (int i = 0; i < 4; ++i) {
      af[i]  = *(const bf16x8*)&lds[cur][0][g4][wr + i * 16 + l16][0];
      bfr[i] = *(const bf16x8*)&lds[cur][1][g4][wc + i * 16 + l16][0];
    }
#pragma unroll
    for (int mi = 0; mi < 4; ++mi)
#pragma unroll
      for (int ni = 0; ni < 4; ++ni)
        acc[mi][ni] =
            __builtin_amdgcn_mfma_f32_16x16x32_bf16(af[mi], bfr[ni], acc[mi][ni], 0, 0, 0);
    __syncthreads();
  }

#pragma unroll
  for (int mi = 0; mi < 4; ++mi) {
#pragma unroll
    for (int ni = 0; ni < 4; ++ni) {
      const int col = tcol + wc + ni * 16 + l16;
      if constexpr (MODE == 4) {
        const int sel = col >> 10;  // wave-uniform (tile is 128-wide, 1024-aligned)
        const int cc = col & 1023;
        const float bcol = (sel == 0 ? bias : sel == 1 ? bias2 : bias3)[cc];
        const int hh = cc >> 6, d = cc & 63;
#pragma unroll
        for (int r = 0; r < 4; ++r) {
          const int row = trow + wr + mi * 16 + g4 * 4 + r;
          const int n = row >> 11, s = row & 2047;
          float v = acc[mi][ni][r] + bcol;
          if (sel == 0) {
            ((__bf16*)outp)[((size_t)((n * HEADS + hh) * SLEN) + s) * HDIM + d] =
                (__bf16)(v * oscale);
          } else if (sel == 1) {
            ((__bf16*)outp2)[((size_t)((n * HEADS + hh) * SLEN) + s) * HDIM + d] = (__bf16)v;
          } else {
            ((__bf16*)outp3)[((size_t)((n * HEADS + hh) * HDIM) + d) * SLEN + s] = (__bf16)v;
          }
        }
      } else if constexpr (MODE == 5) {
#pragma unroll
        for (int r = 0; r < 4; ++r) {
          const int row = trow + wr + mi * 16 + g4 * 4 + r;
          ((float*)outp)[(size_t)kz * M * N + (size_t)row * N + col] = acc[mi][ni][r];
        }
      } else {  // MODE 3
        const float bcol = bias[col];
#pragma unroll
        for (int r = 0; r < 4; ++r) {
          const int row = trow + wr + mi * 16 + g4 * 4 + r;
          ((__bf16*)outp)[(size_t)row * N + col] =
              (__bf16)fmaxf(acc[mi][ni][r] + bcol, 0.0f);
        }
      }
    }
  }
}

// ---------------- flash attention (swapped QK^T, in-register softmax) ----------------
// 8 waves x 16 q-rows = 128 q per block; 512 blocks; 2 blocks/CU (16 waves/CU).
// Q (pre-scaled by log2e/2048), K: [n][h][s][d] bf16 ; Vt: [n][h][d][s] bf16
// Per lane: q = q0+l16, k = kbase+ni*16+4*g4+r -> softmax over k is lane-local +
// deferred-max; PV via P staged [q][k] in wave-private LDS tile.
__global__ __launch_bounds__(512, 4) void attn_k(const __bf16* __restrict__ Q,
                                                 const __bf16* __restrict__ K,
                                                 const __bf16* __restrict__ Vt,
                                                 const int* __restrict__ mask,
                                                 const int* __restrict__ flags,
                                                 __bf16* __restrict__ ctx) {
  const int tid = threadIdx.x, lane = tid & 63, wave = tid >> 6;
  const int l16 = lane & 15, g4 = lane >> 4;
  const int bid = blockIdx.x;
  const int lb = (bid & 7) * 64 + (bid >> 3);  // XCD-chunked (512 blocks)
  const int qt = lb & 15, h = (lb >> 4) & 15, n = lb >> 8;
  const int q0 = qt * 128 + wave * 16;
  const __bf16* Qh = Q + (size_t)(n * HEADS + h) * SLEN * HDIM;
  const __bf16* Kh = K + (size_t)(n * HEADS + h) * SLEN * HDIM;
  const __bf16* Vh = Vt + (size_t)(n * HEADS + h) * HDIM * SLEN;
  const int* Mh = mask + (size_t)n * SLEN * SLEN;
  const int* Fh = flags + (n * 16 + qt) * 32;

  // wave-private P tile: [q(16)][k(64)] bf16, row stride 72 elems (144B)
  __shared__ __align__(16) __bf16 P_lds[8][16][72];

  bf16x8 qf[2];
  qf[0] = *(const bf16x8*)(Qh + (size_t)(q0 + l16) * HDIM + g4 * 8);
  qf[1] = *(const bf16x8*)(Qh + (size_t)(q0 + l16) * HDIM + 32 + g4 * 8);

  float m_ = -INFINITY, lsum = 0.0f;
  f32x4 o[4];
#pragma unroll
  for (int ni = 0; ni < 4; ++ni) o[ni] = (f32x4)0.0f;

  for (int kt = 0; kt < SLEN / 64; ++kt) {
    const int kbase = kt * 64;
    const bool full = Fh[kt] != 0;
    // --- S^T: lane holds one q-column (q=l16), 16 k-rows ---
    f32x4 s[4];
#pragma unroll
    for (int ni = 0; ni < 4; ++ni) s[ni] = (f32x4)0.0f;
#pragma unroll
    for (int ni = 0; ni < 4; ++ni) {
      bf16x8 kf0 = *(const bf16x8*)(Kh + (size_t)(kbase + ni * 16 + l16) * HDIM + g4 * 8);
      bf16x8 kf1 = *(const bf16x8*)(Kh + (size_t)(kbase + ni * 16 + l16) * HDIM + 32 + g4 * 8);
      s[ni] = __builtin_amdgcn_mfma_f32_16x16x32_bf16(kf0, qf[0], s[ni], 0, 0, 0);
      s[ni] = __builtin_amdgcn_mfma_f32_16x16x32_bf16(kf1, qf[1], s[ni], 0, 0, 0);
    }
    if (!full) {  // correctness path (not taken when mask all-ones)
#pragma unroll
      for (int ni = 0; ni < 4; ++ni)
#pragma unroll
        for (int r = 0; r < 4; ++r) {
          const int mk = Mh[(size_t)(q0 + l16) * SLEN + kbase + ni * 16 + 4 * g4 + r];
          s[ni][r] = mk ? s[ni][r] : -INFINITY;
        }
    }
    // --- per-lane max over this lane's 16 k values ---
    float a = fmaxf(fmaxf(s[0][0], s[0][1]), fmaxf(s[0][2], s[0][3]));
    float b = fmaxf(fmaxf(s[1][0], s[1][1]), fmaxf(s[1][2], s[1][3]));
    float c = fmaxf(fmaxf(s[2][0], s[2][1]), fmaxf(s[2][2], s[2][3]));
    float d = fmaxf(fmaxf(s[3][0], s[3][1]), fmaxf(s[3][2], s[3][3]));
    const float pmax = fmaxf(fmaxf(a, b), fmaxf(c, d));
    if (!__all(pmax <= m_ + 8.0f)) {  // rescale (first tile + rare growth)
      float pm = fmaxf(m_, pmax);
      pm = fmaxf(pm, __shfl_xor(pm, 16));
      pm = fmaxf(pm, __shfl_xor(pm, 32));
      const float al = __builtin_amdgcn_exp2f(m_ - pm);
      m_ = pm;
      lsum *= al;
#pragma unroll
      for (int r = 0; r < 4; ++r) {
        const float ao = __shfl(al, 4 * g4 + r);  // alpha for o-row q=4*g4+r
#pragma unroll
        for (int ni = 0; ni < 4; ++ni) o[ni][r] *= ao;
      }
    }
    // --- p = exp2(s - m); partial lsum; pack to LDS [q][k] ---
    float ls = 0.0f;
#pragma unroll
    for (int ni = 0; ni < 4; ++ni) {
      bf16x4 pk;
#pragma unroll
      for (int r = 0; r < 4; ++r) {
        const float p = __builtin_amdgcn_exp2f(s[ni][r] - m_);
        ls += p;
        pk[r] = (__bf16)p;
      }
      *(bf16x4*)&P_lds[wave][l16][ni * 16 + 4 * g4] = pk;
    }
    lsum += ls;
    // --- PV: A = P[q][k] (row=q=l16, k=8*g4+j), B = Vt (col=d, k) ---
#pragma unroll
    for (int kb = 0; kb < 2; ++kb) {
      bf16x8 pa = *(const bf16x8*)&P_lds[wave][l16][kb * 32 + 8 * g4];
#pragma unroll
      for (int ni = 0; ni < 4; ++ni) {
        bf16x8 vf =
            *(const bf16x8*)(Vh + (size_t)(ni * 16 + l16) * SLEN + kbase + kb * 32 + 8 * g4);
        o[ni] = __builtin_amdgcn_mfma_f32_16x16x32_bf16(pa, vf, o[ni], 0, 0, 0);
      }
    }
  }
  // --- epilogue: o row = q0+4*g4+r, col d = ni*16+l16 ---
  {
    float l = lsum;
    l += __shfl_xor(l, 16);
    l += __shfl_xor(l, 32);
    lsum = l;
  }
#pragma unroll
  for (int r = 0; r < 4; ++r) {
    const float inv = __builtin_amdgcn_rcpf(__shfl(lsum, 4 * g4 + r));
#pragma unroll
    for (int ni = 0; ni < 4; ++ni) {
      ctx[((size_t)(n * SLEN) + q0 + 4 * g4 + r) * EMBED + h * HDIM + ni * 16 + l16] =
          (__bf16)(o[ni][r] * inv);
    }
  }
}

// ---------------- fused split-K reduce + bias + residual + LayerNorm ----------------
// v = p0[row] + p1[row] + bias + res[row]; LN(v) -> of (f32) and optionally ob (bf16)
__global__ __launch_bounds__(256) void ln_fused_k(const float* __restrict__ p0,
                                                  const float* __restrict__ p1,
                                                  const float* __restrict__ bias,
                                                  const float* __restrict__ res,
                                                  const float* __restrict__ gw,
                                                  const float* __restrict__ bw,
                                                  float* __restrict__ of,
                                                  __bf16* __restrict__ ob) {
  const int tid = threadIdx.x;
  const size_t row = blockIdx.x;
  float4 v = ((const float4*)(p0 + row * EMBED))[tid];
  float4 v1 = ((const float4*)(p1 + row * EMBED))[tid];
  float4 bb = ((const float4*)bias)[tid];
  float4 rr = ((const float4*)(res + row * EMBED))[tid];
  v.x += v1.x + bb.x + rr.x;
  v.y += v1.y + bb.y + rr.y;
  v.z += v1.z + bb.z + rr.z;
  v.w += v1.w + bb.w + rr.w;
  float s = v.x + v.y + v.z + v.w;
  float sq = v.x * v.x + v.y * v.y + v.z * v.z + v.w * v.w;
#pragma unroll
  for (int off = 1; off < 64; off <<= 1) {
    s += __shfl_xor(s, off);
    sq += __shfl_xor(sq, off);
  }
  __shared__ float red[8];
  if ((tid & 63) == 0) { red[tid >> 6] = s; red[4 + (tid >> 6)] = sq; }
  __syncthreads();
  s = red[0] + red[1] + red[2] + red[3];
  sq = red[4] + red[5] + red[6] + red[7];
  const float mean = s * (1.0f / EMBED);
  const float var = sq * (1.0f / EMBED) - mean * mean;
  const float rstd = rsqrtf(var + 1e-5f);
  float4 gv = ((const float4*)gw)[tid];
  float4 bv2 = ((const float4*)bw)[tid];
  float4 ov;
  ov.x = (v.x - mean) * rstd * gv.x + bv2.x;
  ov.y = (v.y - mean) * rstd * gv.y + bv2.y;
  ov.z = (v.z - mean) * rstd * gv.z + bv2.z;
  ov.w = (v.w - mean) * rstd * gv.w + bv2.w;
  ((float4*)(of + row * EMBED))[tid] = ov;
  if (ob) {
    bf16x4 oh;
    oh.x = (__bf16)ov.x; oh.y = (__bf16)ov.y; oh.z = (__bf16)ov.z; oh.w = (__bf16)ov.w;
    ((bf16x4*)(ob + row * EMBED))[tid] = oh;
  }
}

extern "C" void kernel_launch(void* const* d_in, const int* in_sizes, int n_in,
                              void* d_out, int out_size, void* d_ws, size_t ws_size,
                              hipStream_t stream) {
  (void)in_sizes; (void)n_in; (void)out_size; (void)ws_size;
  const float* x   = (const float*)d_in[0];
  const int*  mask = (const int*)d_in[1];
  const float* Wq = (const float*)d_in[2];  const float* bq  = (const float*)d_in[3];
  const float* Wk = (const float*)d_in[4];  const float* bk  = (const float*)d_in[5];
  const float* Wv = (const float*)d_in[6];  const float* bv  = (const float*)d_in[7];
  const float* Wo = (const float*)d_in[8];  const float* bo  = (const float*)d_in[9];
  const float* g1 = (const float*)d_in[10]; const float* be1 = (const float*)d_in[11];
  const float* g2 = (const float*)d_in[12]; const float* be2 = (const float*)d_in[13];
  const float* W1 = (const float*)d_in[14]; const float* b1  = (const float*)d_in[15];
  const float* W2 = (const float*)d_in[16]; const float* b2  = (const float*)d_in[17];

  char* ws = (char*)d_ws;
  size_t off = 0;
  auto alloc = [&](size_t bytes) -> void* {
    void* p = ws + off;
    off += (bytes + 255) & ~(size_t)255;
    return p;
  };
  __bf16* xb   = (__bf16*)alloc((size_t)ROWS * EMBED * 2);
  // Wqt/Wkt/Wvt contiguous -> one [3072][1024] Bt matrix for the fused QKV GEMM
  __bf16* Wqt  = (__bf16*)alloc((size_t)EMBED * EMBED * 2);
  __bf16* Wkt  = (__bf16*)alloc((size_t)EMBED * EMBED * 2);
  __bf16* Wvt  = (__bf16*)alloc((size_t)EMBED * EMBED * 2);
  __bf16* Wot  = (__bf16*)alloc((size_t)EMBED * EMBED * 2);
  __bf16* W1t  = (__bf16*)alloc((size_t)EMBED * FFDIM * 2);
  __bf16* W2t  = (__bf16*)alloc((size_t)FFDIM * EMBED * 2);
  __bf16* Qb   = (__bf16*)alloc((size_t)ROWS * EMBED * 2);   // 8 MB
  __bf16* Kb   = (__bf16*)alloc((size_t)ROWS * EMBED * 2);   // 8 MB
  __bf16* Vtb  = (__bf16*)alloc((size_t)ROWS * EMBED * 2);   // 8 MB
  __bf16* ctxb = (__bf16*)alloc((size_t)ROWS * EMBED * 2);   // 8 MB
  float* hf     = (float*)alloc((size_t)ROWS * EMBED * 4);
  __bf16* hb    = (__bf16*)alloc((size_t)ROWS * EMBED * 2);
  __bf16* a1    = (__bf16*)alloc((size_t)ROWS * FFDIM * 2);  // 32 MB
  int*   mflags = (int*)alloc(NB * 16 * 32 * sizeof(int));
  // split-K partial buffers (2 x 16 MB f32 each), in dead regions:
  //  - Wo partials: a1 region (a1 written later by FF1, after ln1 consumed partials)
  //  - FF2 partials: Qb..ctxb region (dead after attention; ctx dead after Wo)
  float* pWo = (float*)a1;
  float* pF2 = (float*)Qb;

  cast_f32_bf16<<<ROWS * EMBED / 4 / 256, 256, 0, stream>>>(x, xb, ROWS * EMBED / 4);
  transpose_cast<<<dim3(16, 16), 256, 0, stream>>>(Wq, Wqt, EMBED, EMBED);
  transpose_cast<<<dim3(16, 16), 256, 0, stream>>>(Wk, Wkt, EMBED, EMBED);
  transpose_cast<<<dim3(16, 16), 256, 0, stream>>>(Wv, Wvt, EMBED, EMBED);
  transpose_cast<<<dim3(16, 16), 256, 0, stream>>>(Wo, Wot, EMBED, EMBED);
  transpose_cast<<<dim3(FFDIM / 64, EMBED / 64), 256, 0, stream>>>(W1, W1t, EMBED, FFDIM);
  transpose_cast<<<dim3(EMBED / 64, FFDIM / 64), 256, 0, stream>>>(W2, W2t, FFDIM, EMBED);
  mask_flags_k<<<NB * 16 * 32, 256, 0, stream>>>(mask, mflags);

  // fused QKV: N = 3072, Q pre-scaled by log2e/2048 (exp2-space softmax)
  gemm_bt<4><<<(ROWS / 128) * (3 * EMBED / 128), 256, 0, stream>>>(
      xb, Wqt, bq, bk, bv, Qb, Kb, Vtb, ROWS, 3 * EMBED, EMBED, EMBED, LOG2E / 2048.0f);
  attn_k<<<NB * HEADS * (SLEN / 128), 512, 0, stream>>>(Qb, Kb, Vtb, mask, mflags, ctxb);
  // Wo projection, split-K x2 -> f32 partials; reduce fused into ln1
  gemm_bt<5><<<(ROWS / 128) * (EMBED / 128) * 2, 256, 0, stream>>>(
      ctxb, Wot, nullptr, nullptr, nullptr, pWo, nullptr, nullptr,
      ROWS, EMBED, EMBED, EMBED / 2, 1.0f);
  ln_fused_k<<<ROWS, 256, 0, stream>>>(pWo, pWo + (size_t)ROWS * EMBED, bo, x,
                                       g1, be1, hf, hb);
  gemm_bt<3><<<(ROWS / 128) * (FFDIM / 128), 256, 0, stream>>>(
      hb, W1t, b1, nullptr, nullptr, a1, nullptr, nullptr, ROWS, FFDIM, EMBED, EMBED, 1.0f);
  // FF2, split-K x2 -> f32 partials; reduce fused into ln2
  gemm_bt<5><<<(ROWS / 128) * (EMBED / 128) * 2, 256, 0, stream>>>(
      a1, W2t, nullptr, nullptr, nullptr, pF2, nullptr, nullptr,
      ROWS, EMBED, FFDIM, FFDIM / 2, 1.0f);
  ln_fused_k<<<ROWS, 256, 0, stream>>>(pF2, pF2 + (size_t)ROWS * EMBED, b2, hf,
                                       g2, be2, (float*)d_out, nullptr);
}

// Round 5
// 358.445 us; speedup vs baseline: 1.4444x; 1.4444x over previous
//
#include <hip/hip_runtime.h>
#include <hip/hip_bf16.h>
#include <cstdint>
#include <cstddef>

#define EMBED 1024
#define SLEN  2048
#define NB    2
#define HEADS 16
#define HDIM  64
#define FFDIM 4096
#define ROWS  (NB * SLEN)   // 4096
#define LOG2E 1.4426950408889634f

typedef __attribute__((ext_vector_type(8))) __bf16 bf16x8;
typedef __attribute__((ext_vector_type(4))) __bf16 bf16x4;
typedef __attribute__((ext_vector_type(4))) float  f32x4;

__device__ __forceinline__ void gload_lds16(const void* g, void* l) {
  __builtin_amdgcn_global_load_lds(
      (const __attribute__((address_space(1))) void*)g,
      (__attribute__((address_space(3))) void*)l, 16, 0, 0);
}

// ---------------- cast x: f32 -> bf16 (row-major) ----------------
__global__ __launch_bounds__(256) void cast_f32_bf16(const float* __restrict__ in,
                                                     __bf16* __restrict__ out, int n4) {
  int i = blockIdx.x * 256 + threadIdx.x;
  if (i >= n4) return;
  float4 v = ((const float4*)in)[i];
  bf16x4 o;
  o.x = (__bf16)v.x; o.y = (__bf16)v.y; o.z = (__bf16)v.z; o.w = (__bf16)v.w;
  ((bf16x4*)out)[i] = o;
}

// ---------------- transpose + cast: in[R][C] f32 -> out[C][R] bf16 ----------------
__global__ __launch_bounds__(256) void transpose_cast(const float* __restrict__ in,
                                                      __bf16* __restrict__ out, int R, int C) {
  __shared__ float t[64][65];
  const int tx = threadIdx.x & 63;
  const int ty = threadIdx.x >> 6;  // 0..3
  const int tr = blockIdx.y * 64;   // row tile (R dim)
  const int tc = blockIdx.x * 64;   // col tile (C dim)
#pragma unroll
  for (int i = 0; i < 16; ++i) {
    int a = ty * 16 + i;
    t[a][tx] = in[(size_t)(tr + a) * C + tc + tx];
  }
  __syncthreads();
#pragma unroll
  for (int i = 0; i < 16; ++i) {
    int b = ty * 16 + i;
    out[(size_t)(tc + b) * R + tr + tx] = (__bf16)t[tx][b];
  }
}

// ---------------- mask tile flags: 1 iff all mask!=0 in 128q x 64k tile ----------
// flags[(n*16 + qt)*32 + kt]
__global__ __launch_bounds__(256) void mask_flags_k(const int* __restrict__ mask,
                                                    int* __restrict__ flags) {
  const int b = blockIdx.x;
  const int kt = b & 31, qt = (b >> 5) & 15, n = b >> 9;
  const int tid = threadIdx.x;
  const int* base = mask + ((size_t)n * SLEN + qt * 128) * SLEN + kt * 64;
  const int rw = tid >> 4;
  const int cg = tid & 15;
  int ok = 1;
#pragma unroll
  for (int i = 0; i < 8; ++i) {
    int4 v = ((const int4*)(base + (size_t)(rw + i * 16) * SLEN))[cg];
    ok &= (v.x != 0) & (v.y != 0) & (v.z != 0) & (v.w != 0);
  }
  __shared__ int red;
  if (tid == 0) red = 1;
  __syncthreads();
  if (!ok) red = 0;  // benign race: all writers store 0
  __syncthreads();
  if (tid == 0) flags[b] = red;
}

// ---------------- GEMM: C[M][N] = A[M][K] * Bt[N][K]^T ----------------------------
// MODE 3: out bf16 row-major = relu(acc + bias)
// MODE 4: fused QKV: N=3072; sel=col>>10: 0 -> Q layout [n][h][s][d] * oscale,
//         1 -> K layout [n][h][s][d], 2 -> Vt layout [n][h][d][s]; bias/bias2/bias3.
// MODE 5: split-K partial: grid = tiles*ksplit; kz = bid/tiles; computes K-chunk
//         [kz*Kc, (kz+1)*Kc) and writes raw f32 acc to outp[kz*M*N + row*N + col].
template <int MODE>
__global__ __launch_bounds__(256, 2) void gemm_bt(
    const __bf16* __restrict__ A, const __bf16* __restrict__ Bt,
    const float* __restrict__ bias, const float* __restrict__ bias2,
    const float* __restrict__ bias3,
    void* __restrict__ outp, void* __restrict__ outp2, void* __restrict__ outp3,
    int M, int N, int K, int Kc, float oscale) {
  __shared__ __bf16 lds[2][2][4][128][8];
  const int tid = threadIdx.x;
  const int lane = tid & 63;
  const int ntile = N >> 7;
  int t = blockIdx.x;
  int kz = 0;
  if constexpr (MODE == 5) {
    const int tiles = (M >> 7) * ntile;
    kz = t / tiles;
    t -= kz * tiles;
  }
  const int bm = t / ntile;
  const int bn = t % ntile;
  const int trow = bm << 7;
  const int tcol = bn << 7;

  const int c0 = tid >> 7;
  const int r0 = tid & 127;
  const __bf16* Ag = A + (size_t)(trow + r0) * K + (size_t)kz * Kc + c0 * 8;
  const __bf16* Bg = Bt + (size_t)(tcol + r0) * K + (size_t)kz * Kc + c0 * 8;

  auto stage = [&](int buf, int kt) {
    const __bf16* a0 = Ag + (size_t)kt * 32;
    const __bf16* b0 = Bg + (size_t)kt * 32;
    char* la = (char*)&lds[buf][0][0][0][0] + tid * 16;
    char* lb = (char*)&lds[buf][1][0][0][0] + tid * 16;
    gload_lds16(a0, la);
    gload_lds16(a0 + 16, la + 4096);
    gload_lds16(b0, lb);
    gload_lds16(b0 + 16, lb + 4096);
  };

  const int wave = tid >> 6;
  const int wr = (wave >> 1) * 64;
  const int wc = (wave & 1) * 64;
  const int l16 = lane & 15;
  const int g4 = lane >> 4;

  f32x4 acc[4][4];
#pragma unroll
  for (int i = 0; i < 4; ++i)
#pragma unroll
    for (int j = 0; j < 4; ++j) acc[i][j] = (f32x4)0.0f;

  const int nk = Kc >> 5;
  stage(0, 0);
  for (int kt = 0; kt < nk; ++kt) {
    const int cur = kt & 1;
    if (kt + 1 < nk) stage(cur ^ 1, kt + 1);
    __syncthreads();
    bf16x8 af[4], bfr[4];
#pragma unroll
    for (int i = 0; i < 4; ++i) {
      af[i]  = *(const bf16x8*)&lds[cur][0][g4][wr + i * 16 + l16][0];
      bfr[i] = *(const bf16x8*)&lds[cur][1][g4][wc + i * 16 + l16][0];
    }
#pragma unroll
    for (int mi = 0; mi < 4; ++mi)
#pragma unroll
      for (int ni = 0; ni < 4; ++ni)
        acc[mi][ni] =
            __builtin_amdgcn_mfma_f32_16x16x32_bf16(af[mi], bfr[ni], acc[mi][ni], 0, 0, 0);
    __syncthreads();
  }

#pragma unroll
  for (int mi = 0; mi < 4; ++mi) {
#pragma unroll
    for (int ni = 0; ni < 4; ++ni) {
      const int col = tcol + wc + ni * 16 + l16;
      if constexpr (MODE == 4) {
        const int sel = col >> 10;  // wave-uniform (tile is 128-wide, 1024-aligned)
        const int cc = col & 1023;
        const float bcol = (sel == 0 ? bias : sel == 1 ? bias2 : bias3)[cc];
        const int hh = cc >> 6, d = cc & 63;
#pragma unroll
        for (int r = 0; r < 4; ++r) {
          const int row = trow + wr + mi * 16 + g4 * 4 + r;
          const int n = row >> 11, s = row & 2047;
          float v = acc[mi][ni][r] + bcol;
          if (sel == 0) {
            ((__bf16*)outp)[((size_t)((n * HEADS + hh) * SLEN) + s) * HDIM + d] =
                (__bf16)(v * oscale);
          } else if (sel == 1) {
            ((__bf16*)outp2)[((size_t)((n * HEADS + hh) * SLEN) + s) * HDIM + d] = (__bf16)v;
          } else {
            ((__bf16*)outp3)[((size_t)((n * HEADS + hh) * HDIM) + d) * SLEN + s] = (__bf16)v;
          }
        }
      } else if constexpr (MODE == 5) {
#pragma unroll
        for (int r = 0; r < 4; ++r) {
          const int row = trow + wr + mi * 16 + g4 * 4 + r;
          ((float*)outp)[(size_t)kz * M * N + (size_t)row * N + col] = acc[mi][ni][r];
        }
      } else {  // MODE 3
        const float bcol = bias[col];
#pragma unroll
        for (int r = 0; r < 4; ++r) {
          const int row = trow + wr + mi * 16 + g4 * 4 + r;
          ((__bf16*)outp)[(size_t)row * N + col] =
              (__bf16)fmaxf(acc[mi][ni][r] + bcol, 0.0f);
        }
      }
    }
  }
}

// ---------------- flash attention (LDS-staged K/V, swapped QK^T) ----------------
// 4 waves x 32 q-rows = 128 q per block; 512 blocks (XCD-chunk swizzled).
// Q (pre-scaled by log2e/2048), K: [n][h][s][d] bf16 ; Vt: [n][h][d][s] bf16
// K/V 64-k tiles double-buffered in LDS (chunked [chunk][row][8] layout, staged
// via global_load_lds like the GEMM). Softmax lane-local (S^T) + deferred max.
__global__ __launch_bounds__(256, 2) void attn_k(const __bf16* __restrict__ Q,
                                                 const __bf16* __restrict__ K,
                                                 const __bf16* __restrict__ Vt,
                                                 const int* __restrict__ mask,
                                                 const int* __restrict__ flags,
                                                 __bf16* __restrict__ ctx) {
  const int tid = threadIdx.x, lane = tid & 63, wave = tid >> 6;
  const int l16 = lane & 15, g4 = lane >> 4;
  const int bid = blockIdx.x;
  const int lb = (bid & 7) * 64 + (bid >> 3);  // XCD-chunked (512 blocks)
  const int qt = lb & 15, h = (lb >> 4) & 15, n = lb >> 8;
  const int q0 = qt * 128 + wave * 32;
  const __bf16* Qh = Q + (size_t)(n * HEADS + h) * SLEN * HDIM;
  const __bf16* Kh = K + (size_t)(n * HEADS + h) * SLEN * HDIM;
  const __bf16* Vh = Vt + (size_t)(n * HEADS + h) * HDIM * SLEN;
  const int* Mh = mask + (size_t)n * SLEN * SLEN;
  const int* Fh = flags + (n * 16 + qt) * 32;

  // K/V tiles: [buf][K=0/V=1][chunk(8)][row(64)][8 bf16]; 8KB per matrix per buf
  __shared__ __bf16 KV[2][2][8][64][8];
  // wave-private P tile per mq: [q(16)][k(64)] bf16, row stride 72 elems (144B)
  __shared__ __align__(16) __bf16 P_lds[4][2][16][72];

  // staging: thread -> (row = tid&63, chunk = tid>>6 [+4 on 2nd issue])
  const int srow = tid & 63;
  const int schunk = tid >> 6;
  const __bf16* Kg = Kh + (size_t)srow * HDIM + schunk * 8;
  const __bf16* Vg = Vh + (size_t)srow * SLEN + schunk * 8;
  auto stage = [&](int buf, int kb) {
    char* lk = (char*)&KV[buf][0][0][0][0] + tid * 16;
    char* lv = (char*)&KV[buf][1][0][0][0] + tid * 16;
    const __bf16* kg = Kg + (size_t)kb * 64 * HDIM;
    const __bf16* vg = Vg + kb * 64;
    gload_lds16(kg, lk);
    gload_lds16(kg + 32, lk + 4096);  // chunks 4..7 (cols 32..63)
    gload_lds16(vg, lv);
    gload_lds16(vg + 32, lv + 4096);  // chunks 4..7 (k 32..63)
  };

  bf16x8 qf[2][2];
#pragma unroll
  for (int mq = 0; mq < 2; ++mq)
#pragma unroll
    for (int kd = 0; kd < 2; ++kd)
      qf[mq][kd] =
          *(const bf16x8*)(Qh + (size_t)(q0 + mq * 16 + l16) * HDIM + kd * 32 + g4 * 8);

  float m_[2], lsum[2];
  f32x4 o[2][4];
#pragma unroll
  for (int mq = 0; mq < 2; ++mq) {
    m_[mq] = -INFINITY;
    lsum[mq] = 0.0f;
#pragma unroll
    for (int ni = 0; ni < 4; ++ni) o[mq][ni] = (f32x4)0.0f;
  }

  const int nt = SLEN / 64;
  stage(0, 0);
  for (int kt = 0; kt < nt; ++kt) {
    const int cur = kt & 1;
    const int kbase = kt * 64;
    if (kt + 1 < nt) stage(cur ^ 1, kt + 1);
    __syncthreads();  // tile `cur` staged & visible
    const bool full = Fh[kt] != 0;
    // --- S^T: lane holds one q-column (q=l16), 16 k-rows per mq ---
    f32x4 s[2][4];
#pragma unroll
    for (int mq = 0; mq < 2; ++mq)
#pragma unroll
      for (int ni = 0; ni < 4; ++ni) s[mq][ni] = (f32x4)0.0f;
#pragma unroll
    for (int ni = 0; ni < 4; ++ni) {
      bf16x8 kf0 = *(const bf16x8*)&KV[cur][0][g4][ni * 16 + l16][0];
      bf16x8 kf1 = *(const bf16x8*)&KV[cur][0][4 + g4][ni * 16 + l16][0];
#pragma unroll
      for (int mq = 0; mq < 2; ++mq) {
        s[mq][ni] = __builtin_amdgcn_mfma_f32_16x16x32_bf16(kf0, qf[mq][0], s[mq][ni], 0, 0, 0);
        s[mq][ni] = __builtin_amdgcn_mfma_f32_16x16x32_bf16(kf1, qf[mq][1], s[mq][ni], 0, 0, 0);
      }
    }
    if (!full) {  // correctness path (not taken when mask all-ones)
#pragma unroll
      for (int mq = 0; mq < 2; ++mq)
#pragma unroll
        for (int ni = 0; ni < 4; ++ni)
#pragma unroll
          for (int r = 0; r < 4; ++r) {
            const int mk =
                Mh[(size_t)(q0 + mq * 16 + l16) * SLEN + kbase + ni * 16 + 4 * g4 + r];
            s[mq][ni][r] = mk ? s[mq][ni][r] : -INFINITY;
          }
    }
    // --- per-lane max over this lane's 16 k values (per mq) ---
    float pmax[2];
#pragma unroll
    for (int mq = 0; mq < 2; ++mq) {
      float a = fmaxf(fmaxf(s[mq][0][0], s[mq][0][1]), fmaxf(s[mq][0][2], s[mq][0][3]));
      float b = fmaxf(fmaxf(s[mq][1][0], s[mq][1][1]), fmaxf(s[mq][1][2], s[mq][1][3]));
      float c = fmaxf(fmaxf(s[mq][2][0], s[mq][2][1]), fmaxf(s[mq][2][2], s[mq][2][3]));
      float d = fmaxf(fmaxf(s[mq][3][0], s[mq][3][1]), fmaxf(s[mq][3][2], s[mq][3][3]));
      pmax[mq] = fmaxf(fmaxf(a, b), fmaxf(c, d));
    }
    const int ok = (pmax[0] <= m_[0] + 8.0f) & (pmax[1] <= m_[1] + 8.0f);
    if (!__all(ok)) {  // rescale (first tile + rare growth)
#pragma unroll
      for (int mq = 0; mq < 2; ++mq) {
        float pm = fmaxf(m_[mq], pmax[mq]);
        pm = fmaxf(pm, __shfl_xor(pm, 16));
        pm = fmaxf(pm, __shfl_xor(pm, 32));
        const float al = __builtin_amdgcn_exp2f(m_[mq] - pm);
        m_[mq] = pm;
        lsum[mq] *= al;
#pragma unroll
        for (int r = 0; r < 4; ++r) {
          const float ao = __shfl(al, 4 * g4 + r);  // alpha for o-row q=4*g4+r
#pragma unroll
          for (int ni = 0; ni < 4; ++ni) o[mq][ni][r] *= ao;
        }
      }
    }
    // --- p = exp2(s - m); partial lsum; pack to LDS [q][k] ---
#pragma unroll
    for (int mq = 0; mq < 2; ++mq) {
      float ls = 0.0f;
#pragma unroll
      for (int ni = 0; ni < 4; ++ni) {
        bf16x4 pk;
#pragma unroll
        for (int r = 0; r < 4; ++r) {
          const float p = __builtin_amdgcn_exp2f(s[mq][ni][r] - m_[mq]);
          ls += p;
          pk[r] = (__bf16)p;
        }
        *(bf16x4*)&P_lds[wave][mq][l16][ni * 16 + 4 * g4] = pk;
      }
      lsum[mq] += ls;
    }
    // --- PV: A = P[q][k] (row=q=l16, k=8*g4+j), B = V from LDS (col=d, k) ---
#pragma unroll
    for (int kb = 0; kb < 2; ++kb) {
      bf16x8 pa0 = *(const bf16x8*)&P_lds[wave][0][l16][kb * 32 + 8 * g4];
      bf16x8 pa1 = *(const bf16x8*)&P_lds[wave][1][l16][kb * 32 + 8 * g4];
#pragma unroll
      for (int ni = 0; ni < 4; ++ni) {
        bf16x8 vf = *(const bf16x8*)&KV[cur][1][kb * 4 + g4][ni * 16 + l16][0];
        o[0][ni] = __builtin_amdgcn_mfma_f32_16x16x32_bf16(pa0, vf, o[0][ni], 0, 0, 0);
        o[1][ni] = __builtin_amdgcn_mfma_f32_16x16x32_bf16(pa1, vf, o[1][ni], 0, 0, 0);
      }
    }
    __syncthreads();  // all waves done reading `cur` before restage next iter
  }
  // --- epilogue: o row = q0+mq*16+4*g4+r, col d = ni*16+l16 ---
#pragma unroll
  for (int mq = 0; mq < 2; ++mq) {
    float l = lsum[mq];
    l += __shfl_xor(l, 16);
    l += __shfl_xor(l, 32);
    lsum[mq] = l;
  }
#pragma unroll
  for (int mq = 0; mq < 2; ++mq) {
#pragma unroll
    for (int r = 0; r < 4; ++r) {
      const float inv = __builtin_amdgcn_rcpf(__shfl(lsum[mq], 4 * g4 + r));
#pragma unroll
      for (int ni = 0; ni < 4; ++ni) {
        ctx[((size_t)(n * SLEN) + q0 + mq * 16 + 4 * g4 + r) * EMBED + h * HDIM + ni * 16 +
            l16] = (__bf16)(o[mq][ni][r] * inv);
      }
    }
  }
}

// ---------------- fused split-K reduce + bias + residual + LayerNorm ----------------
// v = p0[row] + p1[row] + bias + res[row]; LN(v) -> of (f32) and optionally ob (bf16)
__global__ __launch_bounds__(256) void ln_fused_k(const float* __restrict__ p0,
                                                  const float* __restrict__ p1,
                                                  const float* __restrict__ bias,
                                                  const float* __restrict__ res,
                                                  const float* __restrict__ gw,
                                                  const float* __restrict__ bw,
                                                  float* __restrict__ of,
                                                  __bf16* __restrict__ ob) {
  const int tid = threadIdx.x;
  const size_t row = blockIdx.x;
  float4 v = ((const float4*)(p0 + row * EMBED))[tid];
  float4 v1 = ((const float4*)(p1 + row * EMBED))[tid];
  float4 bb = ((const float4*)bias)[tid];
  float4 rr = ((const float4*)(res + row * EMBED))[tid];
  v.x += v1.x + bb.x + rr.x;
  v.y += v1.y + bb.y + rr.y;
  v.z += v1.z + bb.z + rr.z;
  v.w += v1.w + bb.w + rr.w;
  float s = v.x + v.y + v.z + v.w;
  float sq = v.x * v.x + v.y * v.y + v.z * v.z + v.w * v.w;
#pragma unroll
  for (int off = 1; off < 64; off <<= 1) {
    s += __shfl_xor(s, off);
    sq += __shfl_xor(sq, off);
  }
  __shared__ float red[8];
  if ((tid & 63) == 0) { red[tid >> 6] = s; red[4 + (tid >> 6)] = sq; }
  __syncthreads();
  s = red[0] + red[1] + red[2] + red[3];
  sq = red[4] + red[5] + red[6] + red[7];
  const float mean = s * (1.0f / EMBED);
  const float var = sq * (1.0f / EMBED) - mean * mean;
  const float rstd = rsqrtf(var + 1e-5f);
  float4 gv = ((const float4*)gw)[tid];
  float4 bv2 = ((const float4*)bw)[tid];
  float4 ov;
  ov.x = (v.x - mean) * rstd * gv.x + bv2.x;
  ov.y = (v.y - mean) * rstd * gv.y + bv2.y;
  ov.z = (v.z - mean) * rstd * gv.z + bv2.z;
  ov.w = (v.w - mean) * rstd * gv.w + bv2.w;
  ((float4*)(of + row * EMBED))[tid] = ov;
  if (ob) {
    bf16x4 oh;
    oh.x = (__bf16)ov.x; oh.y = (__bf16)ov.y; oh.z = (__bf16)ov.z; oh.w = (__bf16)ov.w;
    ((bf16x4*)(ob + row * EMBED))[tid] = oh;
  }
}

extern "C" void kernel_launch(void* const* d_in, const int* in_sizes, int n_in,
                              void* d_out, int out_size, void* d_ws, size_t ws_size,
                              hipStream_t stream) {
  (void)in_sizes; (void)n_in; (void)out_size; (void)ws_size;
  const float* x   = (const float*)d_in[0];
  const int*  mask = (const int*)d_in[1];
  const float* Wq = (const float*)d_in[2];  const float* bq  = (const float*)d_in[3];
  const float* Wk = (const float*)d_in[4];  const float* bk  = (const float*)d_in[5];
  const float* Wv = (const float*)d_in[6];  const float* bv  = (const float*)d_in[7];
  const float* Wo = (const float*)d_in[8];  const float* bo  = (const float*)d_in[9];
  const float* g1 = (const float*)d_in[10]; const float* be1 = (const float*)d_in[11];
  const float* g2 = (const float*)d_in[12]; const float* be2 = (const float*)d_in[13];
  const float* W1 = (const float*)d_in[14]; const float* b1  = (const float*)d_in[15];
  const float* W2 = (const float*)d_in[16]; const float* b2  = (const float*)d_in[17];

  char* ws = (char*)d_ws;
  size_t off = 0;
  auto alloc = [&](size_t bytes) -> void* {
    void* p = ws + off;
    off += (bytes + 255) & ~(size_t)255;
    return p;
  };
  __bf16* xb   = (__bf16*)alloc((size_t)ROWS * EMBED * 2);
  // Wqt/Wkt/Wvt contiguous -> one [3072][1024] Bt matrix for the fused QKV GEMM
  __bf16* Wqt  = (__bf16*)alloc((size_t)EMBED * EMBED * 2);
  __bf16* Wkt  = (__bf16*)alloc((size_t)EMBED * EMBED * 2);
  __bf16* Wvt  = (__bf16*)alloc((size_t)EMBED * EMBED * 2);
  __bf16* Wot  = (__bf16*)alloc((size_t)EMBED * EMBED * 2);
  __bf16* W1t  = (__bf16*)alloc((size_t)EMBED * FFDIM * 2);
  __bf16* W2t  = (__bf16*)alloc((size_t)FFDIM * EMBED * 2);
  __bf16* Qb   = (__bf16*)alloc((size_t)ROWS * EMBED * 2);   // 8 MB
  __bf16* Kb   = (__bf16*)alloc((size_t)ROWS * EMBED * 2);   // 8 MB
  __bf16* Vtb  = (__bf16*)alloc((size_t)ROWS * EMBED * 2);   // 8 MB
  __bf16* ctxb = (__bf16*)alloc((size_t)ROWS * EMBED * 2);   // 8 MB
  float* hf     = (float*)alloc((size_t)ROWS * EMBED * 4);
  __bf16* hb    = (__bf16*)alloc((size_t)ROWS * EMBED * 2);
  __bf16* a1    = (__bf16*)alloc((size_t)ROWS * FFDIM * 2);  // 32 MB
  int*   mflags = (int*)alloc(NB * 16 * 32 * sizeof(int));
  // split-K partial buffers (2 x 16 MB f32 each), in dead regions:
  //  - Wo partials: a1 region (a1 written later by FF1, after ln1 consumed partials)
  //  - FF2 partials: Qb..ctxb region (all dead once FF2 runs)
  float* pWo = (float*)a1;
  float* pF2 = (float*)Qb;

  cast_f32_bf16<<<ROWS * EMBED / 4 / 256, 256, 0, stream>>>(x, xb, ROWS * EMBED / 4);
  transpose_cast<<<dim3(16, 16), 256, 0, stream>>>(Wq, Wqt, EMBED, EMBED);
  transpose_cast<<<dim3(16, 16), 256, 0, stream>>>(Wk, Wkt, EMBED, EMBED);
  transpose_cast<<<dim3(16, 16), 256, 0, stream>>>(Wv, Wvt, EMBED, EMBED);
  transpose_cast<<<dim3(16, 16), 256, 0, stream>>>(Wo, Wot, EMBED, EMBED);
  transpose_cast<<<dim3(FFDIM / 64, EMBED / 64), 256, 0, stream>>>(W1, W1t, EMBED, FFDIM);
  transpose_cast<<<dim3(EMBED / 64, FFDIM / 64), 256, 0, stream>>>(W2, W2t, FFDIM, EMBED);
  mask_flags_k<<<NB * 16 * 32, 256, 0, stream>>>(mask, mflags);

  // fused QKV: N = 3072, Q pre-scaled by log2e/2048 (exp2-space softmax)
  gemm_bt<4><<<(ROWS / 128) * (3 * EMBED / 128), 256, 0, stream>>>(
      xb, Wqt, bq, bk, bv, Qb, Kb, Vtb, ROWS, 3 * EMBED, EMBED, EMBED, LOG2E / 2048.0f);
  attn_k<<<NB * HEADS * (SLEN / 128), 256, 0, stream>>>(Qb, Kb, Vtb, mask, mflags, ctxb);
  // Wo projection, split-K x2 -> f32 partials; reduce fused into ln1
  gemm_bt<5><<<(ROWS / 128) * (EMBED / 128) * 2, 256, 0, stream>>>(
      ctxb, Wot, nullptr, nullptr, nullptr, pWo, nullptr, nullptr,
      ROWS, EMBED, EMBED, EMBED / 2, 1.0f);
  ln_fused_k<<<ROWS, 256, 0, stream>>>(pWo, pWo + (size_t)ROWS * EMBED, bo, x,
                                       g1, be1, hf, hb);
  gemm_bt<3><<<(ROWS / 128) * (FFDIM / 128), 256, 0, stream>>>(
      hb, W1t, b1, nullptr, nullptr, a1, nullptr, nullptr, ROWS, FFDIM, EMBED, EMBED, 1.0f);
  // FF2, split-K x2 -> f32 partials; reduce fused into ln2
  gemm_bt<5><<<(ROWS / 128) * (EMBED / 128) * 2, 256, 0, stream>>>(
      a1, W2t, nullptr, nullptr, nullptr, pF2, nullptr, nullptr,
      ROWS, EMBED, FFDIM, FFDIM / 2, 1.0f);
  ln_fused_k<<<ROWS, 256, 0, stream>>>(pF2, pF2 + (size_t)ROWS * EMBED, b2, hf,
                                       g2, be2, (float*)d_out, nullptr);
}